// Round 3
// baseline (1539.379 us; speedup 1.0000x reference)
//
#include <hip/hip_runtime.h>
#include <cstdint>

// N=100000 nodes, E=1.6M edges (divisible by 32), D=32, 5D=160, ATTR=33
constexpr int D      = 32;
constexpr int FD     = 160;
constexpr int ATTRD  = 33;
constexpr int TILE_E = 32;
constexpr int BLOCK  = 256;   // 4 waves: wave w -> mtile=w>>1, parity=w&1
constexpr int ASTR   = 168;   // sA row stride (shorts): 336 B -> 16B-aligned b128 reads
constexpr int NKS    = 5;     // K-steps of 32 for the 160-K GEMMs
constexpr int AKP    = 72;    // attr-bf16 row stride (shorts), K padded 33->64, +8 pad

typedef __attribute__((ext_vector_type(8))) short short8;  // 8 bf16 (4 VGPRs) MFMA A/B frag
typedef __attribute__((ext_vector_type(4))) float f32x4;   // MFMA C/D frag

__device__ __forceinline__ float fast_tanh(float x) {
    float e = __expf(2.0f * x);
    return 1.0f - 2.0f * __builtin_amdgcn_rcpf(e + 1.0f);
}
// RNE bf16, no NaN handling (inputs are finite by construction)
__device__ __forceinline__ unsigned short bf16rne(float x) {
    union { float f; unsigned u; } v; v.f = x;
    unsigned r = v.u + 0x7fffu + ((v.u >> 16) & 1u);
    return (unsigned short)(r >> 16);
}

// Pack Wd1 (160x160) and W1 (33x32, K zero-padded to 64) into bf16 B-fragment
// lane order. B-chunk (nt,ks): lane L holds B[ks*32 + (L>>4)*8 + j][nt*16 + (L&15)].
// ws layout: [0,25600) shorts = Wd1 frags; [25600, 27648) = W1 frags.
__global__ void prep_weights(const float* __restrict__ Wd1,
                             const float* __restrict__ W1,
                             unsigned short* __restrict__ wsb) {
    int t = blockIdx.x * blockDim.x + threadIdx.x;
    if (t < FD * FD) {
        int k = t / FD, n = t - k * FD;
        int nt = n >> 4, l15 = n & 15;
        int ks = k >> 5, quad = (k >> 3) & 3, j = k & 7;
        int dst = ((nt * NKS + ks) * 64 + quad * 16 + l15) * 8 + j;
        wsb[dst] = bf16rne(Wd1[t]);
    } else if (t < FD * FD + 64 * D) {
        int t2 = t - FD * FD;           // t2 = k*32 + n, k in [0,64)
        int k = t2 >> 5, n = t2 & 31;
        float v = (k < ATTRD) ? W1[k * D + n] : 0.0f;
        int nt = n >> 4, l15 = n & 15;
        int ks = k >> 5, quad = (k >> 3) & 3, j = k & 7;
        int dst = FD * FD + ((nt * 2 + ks) * 64 + quad * 16 + l15) * 8 + j;
        wsb[dst] = bf16rne(v);
    }
}

__global__ __launch_bounds__(BLOCK, 8)
void prop_mfma(const float* __restrict__ xn,
               const float* __restrict__ xe_attr,
               const float* __restrict__ b1,
               const unsigned short* __restrict__ wsb,
               const int*   __restrict__ esrc,
               const int*   __restrict__ edst,
               float* __restrict__ out,
               int E)
{
    // sA (10752 B) doubles as the bf16 attr tile [32][AKP] (4608 B) before the
    // feature phase overwrites it (barrier-separated).
    __shared__ __align__(16) unsigned short sA[TILE_E * ASTR];
    __shared__ __align__(16) float sW[TILE_E * D];             // 4096 B silu(fc1)
    __shared__ float s_b1[D];
    __shared__ float red_s[TILE_E * 2], red_q[TILE_E * 2];
    __shared__ float s_mean[TILE_E], s_scale[TILE_E];
    __shared__ int   s_src[TILE_E], s_dst[TILE_E];
    // total ~16.0 KB -> 8 blocks/CU (thread cap)

    unsigned short* sAttr = sA;   // [32][AKP] bf16, K zero-padded to 64

    const int tid   = threadIdx.x;
    const int lane  = tid & 63;
    const int w     = tid >> 6;
    const int mtile = w >> 1;       // edge rows 16*mtile..+16
    const int par   = w & 1;        // N-tile parity (chunks t: nt = par + 2t)
    const int l15   = lane & 15;
    const int quad  = lane >> 4;
    const long e0   = (long)blockIdx.x * TILE_E;
    const int nvalid = min(TILE_E, (int)((long)E - e0));

    // ---------- stage attr tile as bf16 A-matrix (K padded to 64), b1, idx ----------
    #pragma unroll
    for (int it = 0; it < 8; ++it) {
        int f = tid + BLOCK * it;          // 2048 items: e = f>>6, k = f&63
        int e = f >> 6, k = f & 63;
        float v = (k < ATTRD && e < nvalid) ? xe_attr[(e0 + e) * ATTRD + k] : 0.0f;
        sAttr[e * AKP + k] = bf16rne(v);
    }
    if (tid < D) s_b1[tid] = b1[tid];
    if (tid < TILE_E) {
        s_src[tid] = (tid < nvalid) ? esrc[e0 + tid] : 0;
        s_dst[tid] = (tid < nvalid) ? edst[e0 + tid] : 0;
    }
    __syncthreads();

    // ---------- fc1 via MFMA: W = silu(attr @ W1 + b1) ----------
    {
        const short8* W1p = reinterpret_cast<const short8*>(wsb + FD * FD);
        f32x4 c0 = (f32x4){0.f, 0.f, 0.f, 0.f};
        #pragma unroll
        for (int ks = 0; ks < 2; ++ks) {
            short8 af = *reinterpret_cast<const short8*>(
                &sAttr[(mtile * 16 + l15) * AKP + ks * 32 + quad * 8]);
            short8 bf = W1p[(par * 2 + ks) * 64 + lane];
            c0 = __builtin_amdgcn_mfma_f32_16x16x32_bf16(af, bf, c0, 0, 0, 0);
        }
        int j = par * 16 + l15;
        float bb = s_b1[j];
        #pragma unroll
        for (int r = 0; r < 4; ++r) {
            int e = mtile * 16 + quad * 4 + r;
            float acc = c0[r] + bb;
            sW[e * D + j] = acc * __builtin_amdgcn_rcpf(1.0f + __expf(-acc));
        }
    }
    __syncthreads();

    // ---------- gathers + features + tanh -> sA bf16 [e][k] ----------
    {
        int e  = tid >> 3;
        int c4 = (tid & 7) * 4;
        int rs = s_src[e], rd = s_dst[e];
        float4 vs = *reinterpret_cast<const float4*>(xn + (size_t)rs * D + c4);
        float4 vd = *reinterpret_cast<const float4*>(xn + (size_t)rd * D + c4);
        float4 wv = *reinterpret_cast<const float4*>(&sW[e * D + c4]);
        float g[4], a[4];
        g[0] = wv.x * (vs.x - vd.x); a[0] = wv.x * (vs.x + vd.x) * 0.5f;
        g[1] = wv.y * (vs.y - vd.y); a[1] = wv.y * (vs.y + vd.y) * 0.5f;
        g[2] = wv.z * (vs.z - vd.z); a[2] = wv.z * (vs.z + vd.z) * 0.5f;
        g[3] = wv.w * (vs.w - vd.w); a[3] = wv.w * (vs.w + vd.w) * 0.5f;
        #pragma unroll
        for (int q = 0; q < 5; ++q) {
            ushort4 u;
            unsigned short* up = reinterpret_cast<unsigned short*>(&u);
            #pragma unroll
            for (int i = 0; i < 4; ++i) {
                float f = (q == 0) ? g[i] : (q == 1) ? a[i] : (q == 2) ? g[i] * a[i]
                        : (q == 3) ? g[i] * g[i] : a[i] * a[i];
                up[i] = bf16rne(fast_tanh(f));
            }
            *reinterpret_cast<ushort4*>(&sA[e * ASTR + q * D + c4]) = u;
        }
    }
    __syncthreads();

    const short8* Bp = reinterpret_cast<const short8*>(wsb);
    f32x4 C[5];

    auto run_mm = [&]() {
        #pragma unroll
        for (int t = 0; t < 5; ++t) C[t] = (f32x4){0.f, 0.f, 0.f, 0.f};
        #pragma unroll
        for (int ks = 0; ks < NKS; ++ks) {
            short8 af = *reinterpret_cast<const short8*>(
                &sA[(mtile * 16 + l15) * ASTR + ks * 32 + quad * 8]);
            #pragma unroll
            for (int t = 0; t < 5; ++t) {
                int nt = par + 2 * t;
                short8 bf = Bp[(nt * NKS + ks) * 64 + lane];
                C[t] = __builtin_amdgcn_mfma_f32_16x16x32_bf16(af, bf, C[t], 0, 0, 0);
            }
        }
    };

    // ---------- matmul 1 ----------
    run_mm();

    // ---------- tv_norm stats ----------
    #pragma unroll
    for (int r = 0; r < 4; ++r) {
        float s = C[0][r] + C[1][r] + C[2][r] + C[3][r] + C[4][r];
        float q = C[0][r]*C[0][r] + C[1][r]*C[1][r] + C[2][r]*C[2][r]
                + C[3][r]*C[3][r] + C[4][r]*C[4][r];
        #pragma unroll
        for (int m = 1; m < 16; m <<= 1) {
            s += __shfl_xor(s, m);
            q += __shfl_xor(q, m);
        }
        if (l15 == 0) {
            int row = mtile * 16 + quad * 4 + r;
            red_s[row * 2 + par] = s;
            red_q[row * 2 + par] = q;
        }
    }
    __syncthreads();
    if (tid < TILE_E) {
        float s = red_s[tid * 2] + red_s[tid * 2 + 1];
        float q = red_q[tid * 2] + red_q[tid * 2 + 1];
        float mean = s * (1.0f / FD);
        float var  = q - (float)FD * mean * mean;
        s_mean[tid]  = mean;
        s_scale[tid] = __builtin_amdgcn_rsqf(var + 1e-3f);
    }
    __syncthreads();

    // ---------- tanh(tv_norm(x)) -> sA for matmul 2 ----------
    #pragma unroll
    for (int t = 0; t < 5; ++t) {
        int j = (par + 2 * t) * 16 + l15;
        #pragma unroll
        for (int r = 0; r < 4; ++r) {
            int row = mtile * 16 + quad * 4 + r;
            float v = (C[t][r] - s_mean[row]) * s_scale[row];
            sA[row * ASTR + j] = bf16rne(fast_tanh(v));
        }
    }
    __syncthreads();

    // ---------- matmul 2 ----------
    run_mm();

    // ---------- epilogue: msg = tile(W,5)*tanh(x2); chunk-reduce; scatter atomics ----------
    {
        int c = par * 16 + l15;
        #pragma unroll
        for (int r = 0; r < 4; ++r) {
            int e = mtile * 16 + quad * 4 + r;
            if (e >= nvalid) continue;
            float wv = sW[e * D + c];
            float m0 = fast_tanh(C[0][r]) * wv;
            float m1 = fast_tanh(C[1][r]) * wv;
            float m2 = fast_tanh(C[2][r]) * wv;
            float m3 = fast_tanh(C[3][r]) * wv;
            float m4 = fast_tanh(C[4][r]) * wv;
            float A4 = m1 + m2 + m3 + m4;
            atomicAdd(out + (size_t)s_dst[e] * D + c, m0 + 0.5f * A4);
            atomicAdd(out + (size_t)s_src[e] * D + c, 0.5f * A4 - m0);
        }
    }
}

extern "C" void kernel_launch(void* const* d_in, const int* in_sizes, int n_in,
                              void* d_out, int out_size, void* d_ws, size_t ws_size,
                              hipStream_t stream)
{
    const float* xn   = (const float*)d_in[0];
    const float* attr = (const float*)d_in[1];
    const float* W1   = (const float*)d_in[2];
    const float* b1   = (const float*)d_in[3];
    const float* Wd1  = (const float*)d_in[4];
    const int*   esrc = (const int*)d_in[5];
    const int*   edst = (const int*)d_in[6];
    float* out = (float*)d_out;
    unsigned short* wsb = (unsigned short*)d_ws;   // 27648 bf16 = 55.3 KB packed B-frags

    const int E = in_sizes[5];

    hipMemsetAsync(d_out, 0, (size_t)out_size * sizeof(float), stream);
    prep_weights<<<(FD * FD + 64 * D + 255) / 256, 256, 0, stream>>>(Wd1, W1, wsb);
    const int grid = (E + TILE_E - 1) / TILE_E;
    prop_mfma<<<grid, BLOCK, 0, stream>>>(xn, attr, b1, wsb, esrc, edst, out, E);
}

// Round 4
// 1056.167 us; speedup vs baseline: 1.4575x; 1.4575x over previous
//
#include <hip/hip_runtime.h>
#include <cstdint>

// N=100000 nodes, E=1.6M edges (divisible by 32), D=32, 5D=160, ATTR=33
constexpr int D      = 32;
constexpr int FD     = 160;
constexpr int ATTRD  = 33;
constexpr int TILE_E = 32;
constexpr int BLOCK  = 256;   // 4 waves: wave w -> mtile=w>>1, parity=w&1
constexpr int ASTR   = 168;   // sA row stride (shorts): 336 B -> 16B-aligned b128 reads
constexpr int NKS    = 5;     // K-steps of 32 for the 160-K GEMMs
constexpr int AKP    = 72;    // attr-bf16 row stride (shorts), K padded 33->64, +8 pad

typedef __attribute__((ext_vector_type(8))) short short8;  // 8 bf16 (4 VGPRs) MFMA A/B frag
typedef __attribute__((ext_vector_type(4))) float f32x4;   // MFMA C/D frag

__device__ __forceinline__ float fast_tanh(float x) {
    float e = __expf(2.0f * x);
    return 1.0f - 2.0f * __builtin_amdgcn_rcpf(e + 1.0f);
}
// RNE bf16, no NaN handling (inputs are finite by construction)
__device__ __forceinline__ unsigned short bf16rne(float x) {
    union { float f; unsigned u; } v; v.f = x;
    unsigned r = v.u + 0x7fffu + ((v.u >> 16) & 1u);
    return (unsigned short)(r >> 16);
}

// Pack Wd1 (160x160) and W1 (33x32, K zero-padded to 64) into bf16 B-fragment
// lane order. B-chunk (nt,ks): lane L holds B[ks*32 + (L>>4)*8 + j][nt*16 + (L&15)].
// ws layout: [0,25600) shorts = Wd1 frags; [25600, 27648) = W1 frags.
__global__ void prep_weights(const float* __restrict__ Wd1,
                             const float* __restrict__ W1,
                             unsigned short* __restrict__ wsb) {
    int t = blockIdx.x * blockDim.x + threadIdx.x;
    if (t < FD * FD) {
        int k = t / FD, n = t - k * FD;
        int nt = n >> 4, l15 = n & 15;
        int ks = k >> 5, quad = (k >> 3) & 3, j = k & 7;
        int dst = ((nt * NKS + ks) * 64 + quad * 16 + l15) * 8 + j;
        wsb[dst] = bf16rne(Wd1[t]);
    } else if (t < FD * FD + 64 * D) {
        int t2 = t - FD * FD;           // t2 = k*32 + n, k in [0,64)
        int k = t2 >> 5, n = t2 & 31;
        float v = (k < ATTRD) ? W1[k * D + n] : 0.0f;
        int nt = n >> 4, l15 = n & 15;
        int ks = k >> 5, quad = (k >> 3) & 3, j = k & 7;
        int dst = FD * FD + ((nt * 2 + ks) * 64 + quad * 16 + l15) * 8 + j;
        wsb[dst] = bf16rne(v);
    }
}

// launch_bounds(256,4): VGPR cap 128 — compiler lands ~56-72, HW then gives
// floor(512/VGPR) = 7-8 waves/EU naturally. (256,8) capped VGPR at 64 -> 32
// -> scratch spills -> 3.6 GB HBM traffic (round-3 regression).
__global__ __launch_bounds__(BLOCK, 4)
void prop_mfma(const float* __restrict__ xn,
               const float* __restrict__ xe_attr,
               const float* __restrict__ b1,
               const unsigned short* __restrict__ wsb,
               const int*   __restrict__ esrc,
               const int*   __restrict__ edst,
               float* __restrict__ out,
               int E)
{
    // sA (10752 B) doubles as the bf16 attr tile [32][AKP] (4608 B) before the
    // feature phase overwrites it (barrier-separated).
    __shared__ __align__(16) unsigned short sA[TILE_E * ASTR];
    __shared__ __align__(16) float sW[TILE_E * D];             // 4096 B silu(fc1)
    __shared__ float s_b1[D];
    __shared__ float red_s[TILE_E * 2], red_q[TILE_E * 2];
    __shared__ float s_mean[TILE_E], s_scale[TILE_E];
    __shared__ int   s_src[TILE_E], s_dst[TILE_E];
    // total ~16.0 KB -> 8 blocks/CU (thread cap)

    unsigned short* sAttr = sA;   // [32][AKP] bf16, K zero-padded to 64

    const int tid   = threadIdx.x;
    const int lane  = tid & 63;
    const int w     = tid >> 6;
    const int mtile = w >> 1;       // edge rows 16*mtile..+16
    const int par   = w & 1;        // N-tile parity (chunks t: nt = par + 2t)
    const int l15   = lane & 15;
    const int quad  = lane >> 4;
    const long e0   = (long)blockIdx.x * TILE_E;
    const int nvalid = min(TILE_E, (int)((long)E - e0));

    // ---------- stage attr tile as bf16 A-matrix (K padded to 64), b1, idx ----------
    #pragma unroll
    for (int it = 0; it < 8; ++it) {
        int f = tid + BLOCK * it;          // 2048 items: e = f>>6, k = f&63
        int e = f >> 6, k = f & 63;
        float v = (k < ATTRD && e < nvalid) ? xe_attr[(e0 + e) * ATTRD + k] : 0.0f;
        sAttr[e * AKP + k] = bf16rne(v);
    }
    if (tid < D) s_b1[tid] = b1[tid];
    if (tid < TILE_E) {
        s_src[tid] = (tid < nvalid) ? esrc[e0 + tid] : 0;
        s_dst[tid] = (tid < nvalid) ? edst[e0 + tid] : 0;
    }
    __syncthreads();

    // ---------- fc1 via MFMA: W = silu(attr @ W1 + b1) ----------
    {
        const short8* W1p = reinterpret_cast<const short8*>(wsb + FD * FD);
        f32x4 c0 = (f32x4){0.f, 0.f, 0.f, 0.f};
        #pragma unroll
        for (int ks = 0; ks < 2; ++ks) {
            short8 af = *reinterpret_cast<const short8*>(
                &sAttr[(mtile * 16 + l15) * AKP + ks * 32 + quad * 8]);
            short8 bf = W1p[(par * 2 + ks) * 64 + lane];
            c0 = __builtin_amdgcn_mfma_f32_16x16x32_bf16(af, bf, c0, 0, 0, 0);
        }
        int j = par * 16 + l15;
        float bb = s_b1[j];
        #pragma unroll
        for (int r = 0; r < 4; ++r) {
            int e = mtile * 16 + quad * 4 + r;
            float acc = c0[r] + bb;
            sW[e * D + j] = acc * __builtin_amdgcn_rcpf(1.0f + __expf(-acc));
        }
    }
    __syncthreads();

    // ---------- gathers + features + tanh -> sA bf16 [e][k] ----------
    {
        int e  = tid >> 3;
        int c4 = (tid & 7) * 4;
        int rs = s_src[e], rd = s_dst[e];
        float4 vs = *reinterpret_cast<const float4*>(xn + (size_t)rs * D + c4);
        float4 vd = *reinterpret_cast<const float4*>(xn + (size_t)rd * D + c4);
        float4 wv = *reinterpret_cast<const float4*>(&sW[e * D + c4]);
        float g[4], a[4];
        g[0] = wv.x * (vs.x - vd.x); a[0] = wv.x * (vs.x + vd.x) * 0.5f;
        g[1] = wv.y * (vs.y - vd.y); a[1] = wv.y * (vs.y + vd.y) * 0.5f;
        g[2] = wv.z * (vs.z - vd.z); a[2] = wv.z * (vs.z + vd.z) * 0.5f;
        g[3] = wv.w * (vs.w - vd.w); a[3] = wv.w * (vs.w + vd.w) * 0.5f;
        #pragma unroll
        for (int q = 0; q < 5; ++q) {
            ushort4 u;
            unsigned short* up = reinterpret_cast<unsigned short*>(&u);
            #pragma unroll
            for (int i = 0; i < 4; ++i) {
                float f = (q == 0) ? g[i] : (q == 1) ? a[i] : (q == 2) ? g[i] * a[i]
                        : (q == 3) ? g[i] * g[i] : a[i] * a[i];
                up[i] = bf16rne(fast_tanh(f));
            }
            *reinterpret_cast<ushort4*>(&sA[e * ASTR + q * D + c4]) = u;
        }
    }
    __syncthreads();

    const short8* Bp = reinterpret_cast<const short8*>(wsb);
    f32x4 C[5];

    auto run_mm = [&]() {
        #pragma unroll
        for (int t = 0; t < 5; ++t) C[t] = (f32x4){0.f, 0.f, 0.f, 0.f};
        #pragma unroll
        for (int ks = 0; ks < NKS; ++ks) {
            short8 af = *reinterpret_cast<const short8*>(
                &sA[(mtile * 16 + l15) * ASTR + ks * 32 + quad * 8]);
            #pragma unroll
            for (int t = 0; t < 5; ++t) {
                int nt = par + 2 * t;
                short8 bf = Bp[(nt * NKS + ks) * 64 + lane];
                C[t] = __builtin_amdgcn_mfma_f32_16x16x32_bf16(af, bf, C[t], 0, 0, 0);
            }
        }
    };

    // ---------- matmul 1 ----------
    run_mm();

    // ---------- tv_norm stats ----------
    #pragma unroll
    for (int r = 0; r < 4; ++r) {
        float s = C[0][r] + C[1][r] + C[2][r] + C[3][r] + C[4][r];
        float q = C[0][r]*C[0][r] + C[1][r]*C[1][r] + C[2][r]*C[2][r]
                + C[3][r]*C[3][r] + C[4][r]*C[4][r];
        #pragma unroll
        for (int m = 1; m < 16; m <<= 1) {
            s += __shfl_xor(s, m);
            q += __shfl_xor(q, m);
        }
        if (l15 == 0) {
            int row = mtile * 16 + quad * 4 + r;
            red_s[row * 2 + par] = s;
            red_q[row * 2 + par] = q;
        }
    }
    __syncthreads();
    if (tid < TILE_E) {
        float s = red_s[tid * 2] + red_s[tid * 2 + 1];
        float q = red_q[tid * 2] + red_q[tid * 2 + 1];
        float mean = s * (1.0f / FD);
        float var  = q - (float)FD * mean * mean;
        s_mean[tid]  = mean;
        s_scale[tid] = __builtin_amdgcn_rsqf(var + 1e-3f);
    }
    __syncthreads();

    // ---------- tanh(tv_norm(x)) -> sA for matmul 2 ----------
    #pragma unroll
    for (int t = 0; t < 5; ++t) {
        int j = (par + 2 * t) * 16 + l15;
        #pragma unroll
        for (int r = 0; r < 4; ++r) {
            int row = mtile * 16 + quad * 4 + r;
            float v = (C[t][r] - s_mean[row]) * s_scale[row];
            sA[row * ASTR + j] = bf16rne(fast_tanh(v));
        }
    }
    __syncthreads();

    // ---------- matmul 2 ----------
    run_mm();

    // ---------- epilogue: msg = tile(W,5)*tanh(x2); chunk-reduce; scatter atomics ----------
    {
        int c = par * 16 + l15;
        #pragma unroll
        for (int r = 0; r < 4; ++r) {
            int e = mtile * 16 + quad * 4 + r;
            if (e >= nvalid) continue;
            float wv = sW[e * D + c];
            float m0 = fast_tanh(C[0][r]) * wv;
            float m1 = fast_tanh(C[1][r]) * wv;
            float m2 = fast_tanh(C[2][r]) * wv;
            float m3 = fast_tanh(C[3][r]) * wv;
            float m4 = fast_tanh(C[4][r]) * wv;
            float A4 = m1 + m2 + m3 + m4;
            atomicAdd(out + (size_t)s_dst[e] * D + c, m0 + 0.5f * A4);
            atomicAdd(out + (size_t)s_src[e] * D + c, 0.5f * A4 - m0);
        }
    }
}

extern "C" void kernel_launch(void* const* d_in, const int* in_sizes, int n_in,
                              void* d_out, int out_size, void* d_ws, size_t ws_size,
                              hipStream_t stream)
{
    const float* xn   = (const float*)d_in[0];
    const float* attr = (const float*)d_in[1];
    const float* W1   = (const float*)d_in[2];
    const float* b1   = (const float*)d_in[3];
    const float* Wd1  = (const float*)d_in[4];
    const int*   esrc = (const int*)d_in[5];
    const int*   edst = (const int*)d_in[6];
    float* out = (float*)d_out;
    unsigned short* wsb = (unsigned short*)d_ws;   // 27648 bf16 = 55.3 KB packed B-frags

    const int E = in_sizes[5];

    hipMemsetAsync(d_out, 0, (size_t)out_size * sizeof(float), stream);
    prep_weights<<<(FD * FD + 64 * D + 255) / 256, 256, 0, stream>>>(Wd1, W1, wsb);
    const int grid = (E + TILE_E - 1) / TILE_E;
    prop_mfma<<<grid, BLOCK, 0, stream>>>(xn, attr, b1, wsb, esrc, edst, out, E);
}

// Round 5
// 888.331 us; speedup vs baseline: 1.7329x; 1.1889x over previous
//
#include <hip/hip_runtime.h>
#include <cstdint>

// N=100000 nodes, E=1.6M edges, D=32, 5D=160, ATTR=33
constexpr int D      = 32;
constexpr int FD     = 160;
constexpr int ATTRD  = 33;
constexpr int WTILE  = 16;    // edges per wave (fully independent waves, no barriers)
constexpr int BLOCK  = 256;   // 4 waves/block, wave w -> tile blockIdx*4+w
constexpr int NKS    = 5;     // K-steps of 32 for the 160-K GEMMs
constexpr int ASTR   = 168;   // per-wave X2 row stride (shorts): 336 B, 16B-aligned b128 reads

typedef __attribute__((ext_vector_type(8))) short short8;  // 8 bf16 (4 VGPRs) MFMA A/B frag
typedef __attribute__((ext_vector_type(4))) float f32x4;   // MFMA C/D frag

__device__ __forceinline__ float fast_tanh(float x) {
    float e = __expf(2.0f * x);
    return 1.0f - 2.0f * __builtin_amdgcn_rcpf(e + 1.0f);
}
// RNE bf16, no NaN handling (inputs finite by construction)
__device__ __forceinline__ unsigned short bf16rne(float x) {
    union { float f; unsigned u; } v; v.f = x;
    unsigned r = v.u + 0x7fffu + ((v.u >> 16) & 1u);
    return (unsigned short)(r >> 16);
}

// Pack Wd1 (160x160) and W1 rows 0..31 (32x32) into bf16 B-fragment lane order.
// B-chunk (nt,ks): lane L holds B[ks*32 + (L>>4)*8 + j][nt*16 + (L&15)], j<8.
// ws layout (shorts): [0, 25600) Wd1 frags; [25600, 26624) W1 frags (K=32).
// W1 row 32 is applied as a rank-1 VALU correction in the kernel.
__global__ void prep_weights(const float* __restrict__ Wd1,
                             const float* __restrict__ W1,
                             unsigned short* __restrict__ wsb) {
    int t = blockIdx.x * blockDim.x + threadIdx.x;
    if (t < FD * FD) {
        int k = t / FD, n = t - k * FD;
        int nt = n >> 4, l15 = n & 15;
        int ks = k >> 5, quad = (k >> 3) & 3, j = k & 7;
        int dst = ((nt * NKS + ks) * 64 + quad * 16 + l15) * 8 + j;
        wsb[dst] = bf16rne(Wd1[t]);
    } else if (t < FD * FD + 32 * D) {
        int t2 = t - FD * FD;            // t2 = k*32 + n, k in [0,32)
        int k = t2 >> 5, n = t2 & 31;
        int nt = n >> 4, l15 = n & 15;
        int quad = k >> 3, j = k & 7;
        int dst = FD * FD + (nt * 64 + quad * 16 + l15) * 8 + j;
        wsb[dst] = bf16rne(W1[k * D + n]);
    }
}

// (256,4): VGPR cap 128. (256,8) caused scratch spills (R3: 3.6 GB HBM). No
// __syncthreads anywhere: each wave owns 16 edges end-to-end; LDS regions are
// per-wave, same-wave ds_write->ds_read ordering is guaranteed by lgkmcnt.
__global__ __launch_bounds__(BLOCK, 4)
void prop_mfma(const float* __restrict__ xn,
               const float* __restrict__ xe_attr,
               const float* __restrict__ W1,
               const float* __restrict__ b1,
               const unsigned short* __restrict__ wsb,
               const int*   __restrict__ esrc,
               const int*   __restrict__ edst,
               float* __restrict__ out,
               int E)
{
    __shared__ __align__(16) unsigned short sA_all[4 * WTILE * ASTR]; // 21504 B X2 (bf16)
    __shared__ __align__(16) float          sW_all[4 * WTILE * D];    //  8192 B silu(fc1)
    // total ~29.7 KB; occupancy bound by VGPR (~4 waves/SIMD), not LDS

    const int tid  = threadIdx.x;
    const int lane = tid & 63;
    const int w    = tid >> 6;
    const int l15  = lane & 15;
    const int quad = lane >> 4;
    unsigned short* sA = sA_all + w * WTILE * ASTR;
    float*          sW = sW_all + w * WTILE * D;

    const long tile = (long)blockIdx.x * 4 + w;
    const long e0   = tile * WTILE;
    if (e0 >= (long)E) return;                      // wave-uniform, no barriers to miss
    const int nv = min(WTILE, (int)((long)E - e0));

    const short8* Bp  = reinterpret_cast<const short8*>(wsb);
    const short8* W1p = reinterpret_cast<const short8*>(wsb + FD * FD);

    // ---------------- fc1: W = silu(attr @ W1 + b1), A-frag direct from global ----
    {
        int rowA = (int)e0 + ((l15 < nv) ? l15 : 0);
        const float* ar = xe_attr + (size_t)rowA * ATTRD + quad * 8;
        union { short8 v; unsigned short u[8]; } AF0;
        #pragma unroll
        for (int j = 0; j < 8; ++j) AF0.u[j] = bf16rne(ar[j]);

        f32x4 c0 = (f32x4){0.f, 0.f, 0.f, 0.f};
        f32x4 c1 = (f32x4){0.f, 0.f, 0.f, 0.f};
        c0 = __builtin_amdgcn_mfma_f32_16x16x32_bf16(AF0.v, W1p[lane],      c0, 0, 0, 0);
        c1 = __builtin_amdgcn_mfma_f32_16x16x32_bf16(AF0.v, W1p[64 + lane], c1, 0, 0, 0);

        // rank-1 correction for attr col 32, + bias, + silu
        float b1a  = b1[l15],            b1b  = b1[16 + l15];
        float w32a = W1[32 * D + l15],   w32b = W1[32 * D + 16 + l15];
        #pragma unroll
        for (int r = 0; r < 4; ++r) {
            int e = quad * 4 + r;
            int rowC = (int)e0 + ((e < nv) ? e : 0);
            float a32 = xe_attr[(size_t)rowC * ATTRD + 32];
            float x0 = c0[r] + b1a + a32 * w32a;
            float x1 = c1[r] + b1b + a32 * w32b;
            sW[e * D + l15]      = x0 * __builtin_amdgcn_rcpf(1.0f + __expf(-x0));
            sW[e * D + 16 + l15] = x1 * __builtin_amdgcn_rcpf(1.0f + __expf(-x1));
        }
    }

    // ---------------- features: lane owns edge l15, cols quad*8..+8 ----------------
    // A-frags for mm1 chunk ks=q are exactly this lane's feature q values.
    union { short8 v; unsigned short u[8]; } AF[5];
    {
        int ei = (int)e0 + ((l15 < nv) ? l15 : 0);
        int se = esrc[ei], de = edst[ei];
        const float4* xsr = reinterpret_cast<const float4*>(xn + (size_t)se * D + quad * 8);
        const float4* xdr = reinterpret_cast<const float4*>(xn + (size_t)de * D + quad * 8);
        float4 xs0 = xsr[0], xs1 = xsr[1];
        float4 xd0 = xdr[0], xd1 = xdr[1];
        float4 wv0 = *reinterpret_cast<const float4*>(&sW[l15 * D + quad * 8]);
        float4 wv1 = *reinterpret_cast<const float4*>(&sW[l15 * D + quad * 8 + 4]);
        float xs[8] = {xs0.x, xs0.y, xs0.z, xs0.w, xs1.x, xs1.y, xs1.z, xs1.w};
        float xd[8] = {xd0.x, xd0.y, xd0.z, xd0.w, xd1.x, xd1.y, xd1.z, xd1.w};
        float wf[8] = {wv0.x, wv0.y, wv0.z, wv0.w, wv1.x, wv1.y, wv1.z, wv1.w};
        #pragma unroll
        for (int c = 0; c < 8; ++c) {
            float g = wf[c] * (xs[c] - xd[c]);
            float a = wf[c] * (xs[c] + xd[c]) * 0.5f;
            AF[0].u[c] = bf16rne(fast_tanh(g));
            AF[1].u[c] = bf16rne(fast_tanh(a));
            AF[2].u[c] = bf16rne(fast_tanh(g * a));
            AF[3].u[c] = bf16rne(fast_tanh(g * g));
            AF[4].u[c] = bf16rne(fast_tanh(a * a));
        }
    }

    // ---------------- matmul 1: C[nt] (16 edges x 160 cols per wave) ----------------
    f32x4 C[10];
    #pragma unroll
    for (int t = 0; t < 10; ++t) C[t] = (f32x4){0.f, 0.f, 0.f, 0.f};
    #pragma unroll
    for (int ks = 0; ks < NKS; ++ks)
        #pragma unroll
        for (int nt = 0; nt < 10; ++nt)
            C[nt] = __builtin_amdgcn_mfma_f32_16x16x32_bf16(
                AF[ks].v, Bp[(nt * NKS + ks) * 64 + lane], C[nt], 0, 0, 0);

    // ---------------- tv_norm: full row in 16-lane group, shfl-only ----------------
    float mean[4], scale[4];
    #pragma unroll
    for (int r = 0; r < 4; ++r) {
        float s = 0.f, q = 0.f;
        #pragma unroll
        for (int t = 0; t < 10; ++t) { float v = C[t][r]; s += v; q += v * v; }
        #pragma unroll
        for (int m = 1; m < 16; m <<= 1) { s += __shfl_xor(s, m); q += __shfl_xor(q, m); }
        mean[r] = s * (1.0f / FD);
        scale[r] = __builtin_amdgcn_rsqf(q - (float)FD * mean[r] * mean[r] + 1e-3f);
    }

    // ---------------- tanh(tv_norm) -> wave-local LDS (transpose for mm2 A) --------
    #pragma unroll
    for (int t = 0; t < 10; ++t)
        #pragma unroll
        for (int r = 0; r < 4; ++r) {
            float v = fast_tanh((C[t][r] - mean[r]) * scale[r]);
            sA[(quad * 4 + r) * ASTR + t * 16 + l15] = bf16rne(v);
        }

    // ---------------- matmul 2 (A from wave-local LDS, same-wave ordering) ---------
    #pragma unroll
    for (int t = 0; t < 10; ++t) C[t] = (f32x4){0.f, 0.f, 0.f, 0.f};
    #pragma unroll
    for (int ks = 0; ks < NKS; ++ks) {
        short8 af2 = *reinterpret_cast<const short8*>(&sA[l15 * ASTR + ks * 32 + quad * 8]);
        #pragma unroll
        for (int nt = 0; nt < 10; ++nt)
            C[nt] = __builtin_amdgcn_mfma_f32_16x16x32_bf16(
                af2, Bp[(nt * NKS + ks) * 64 + lane], C[nt], 0, 0, 0);
    }

    // ---------------- epilogue: msg = tile(W,5)*tanh; chunk-reduce; atomics --------
    #pragma unroll
    for (int r = 0; r < 4; ++r) {
        int e = quad * 4 + r;
        if (e >= nv) continue;
        int sd = edst[e0 + e], ss = esrc[e0 + e];
        #pragma unroll
        for (int par = 0; par < 2; ++par) {
            int c = par * 16 + l15;
            float wv = sW[e * D + c];
            float m0 = fast_tanh(C[par][r]) * wv;
            float A4 = (fast_tanh(C[par + 2][r]) + fast_tanh(C[par + 4][r])
                      + fast_tanh(C[par + 6][r]) + fast_tanh(C[par + 8][r])) * wv;
            atomicAdd(out + (size_t)sd * D + c, m0 + 0.5f * A4);
            atomicAdd(out + (size_t)ss * D + c, 0.5f * A4 - m0);
        }
    }
}

extern "C" void kernel_launch(void* const* d_in, const int* in_sizes, int n_in,
                              void* d_out, int out_size, void* d_ws, size_t ws_size,
                              hipStream_t stream)
{
    const float* xn   = (const float*)d_in[0];
    const float* attr = (const float*)d_in[1];
    const float* W1   = (const float*)d_in[2];
    const float* b1   = (const float*)d_in[3];
    const float* Wd1  = (const float*)d_in[4];
    const int*   esrc = (const int*)d_in[5];
    const int*   edst = (const int*)d_in[6];
    float* out = (float*)d_out;
    unsigned short* wsb = (unsigned short*)d_ws;   // 26624 bf16 packed B-frags

    const int E = in_sizes[5];

    hipMemsetAsync(d_out, 0, (size_t)out_size * sizeof(float), stream);
    prep_weights<<<(FD * FD + 32 * D + 255) / 256, 256, 0, stream>>>(Wd1, W1, wsb);
    const long tiles = ((long)E + WTILE - 1) / WTILE;
    const int grid = (int)((tiles + 3) / 4);
    prop_mfma<<<grid, BLOCK, 0, stream>>>(xn, attr, W1, b1, wsb, esrc, edst, out, E);
}